// Round 10
// baseline (985.376 us; speedup 1.0000x reference)
//
#include <hip/hip_runtime.h>
#include <hip/hip_fp16.h>
#include <math.h>

#define NB 32
#define NM 8
#define NS 4
#define HOBJ 1024

// ---------- complex helpers ----------
__device__ __forceinline__ float2 cmul(float2 a, float2 b) {
    return make_float2(fmaf(a.x, b.x, -a.y * b.y), fmaf(a.x, b.y, a.y * b.x));
}
__device__ __forceinline__ float2 h2f(__half2 h) {
    return make_float2(__low2float(h), __high2float(h));
}
__device__ __forceinline__ __half2 f2h(float2 v) {
    return __floats2half2_rn(v.x, v.y);
}

// cos/sin(2*pi*j/16) for j=0..9
__constant__ float COS16[10] = {1.f, 0.9238795325f, 0.7071067812f, 0.3826834324f, 0.f,
                                -0.3826834324f, -0.7071067812f, -0.9238795325f, -1.f, -0.9238795325f};
__constant__ float SIN16[10] = {0.f, 0.3826834324f, 0.7071067812f, 0.9238795325f, 1.f,
                                0.9238795325f, 0.7071067812f, 0.3826834324f, 0.f, -0.3826834324f};

template <int S>
__device__ __forceinline__ void dft4(float2 a, float2 b, float2 c, float2 d,
                                     float2* o0, float2* o1, float2* o2, float2* o3) {
    float2 apc = make_float2(a.x + c.x, a.y + c.y);
    float2 amc = make_float2(a.x - c.x, a.y - c.y);
    float2 bpd = make_float2(b.x + d.x, b.y + d.y);
    float2 bmd = make_float2(b.x - d.x, b.y - d.y);
    float2 ib = (S < 0) ? make_float2(bmd.y, -bmd.x) : make_float2(-bmd.y, bmd.x);
    *o0 = make_float2(apc.x + bpd.x, apc.y + bpd.y);
    *o1 = make_float2(amc.x + ib.x, amc.y + ib.y);
    *o2 = make_float2(apc.x - bpd.x, apc.y - bpd.y);
    *o3 = make_float2(amc.x - ib.x, amc.y - ib.y);
}

template <int S>
__device__ __forceinline__ void fft16(float2 v[16]) {
    float2 t[16];
#pragma unroll
    for (int b = 0; b < 4; ++b)
        dft4<S>(v[b], v[4 + b], v[8 + b], v[12 + b],
                &t[4 * b + 0], &t[4 * b + 1], &t[4 * b + 2], &t[4 * b + 3]);
#pragma unroll
    for (int b = 1; b < 4; ++b)
#pragma unroll
        for (int c = 1; c < 4; ++c) {
            int j = b * c;
            float2 w = make_float2(COS16[j], (S < 0) ? -SIN16[j] : SIN16[j]);
            t[4 * b + c] = cmul(t[4 * b + c], w);
        }
#pragma unroll
    for (int c = 0; c < 4; ++c)
        dft4<S>(t[c], t[4 + c], t[8 + c], t[12 + c],
                &v[c + 0], &v[c + 4], &v[c + 8], &v[c + 12]);
}

__device__ __forceinline__ float2 twiddle_base(int S, int t) {
    float sn, cs;
    __sincosf((float)S * 0.0245436926f /*2pi/256*/ * (float)t, &sn, &cs);
    return make_float2(cs, sn);
}

// 256-point FFT, wave-synchronous: 16-lane group inside ONE wave.
// Input v[n1] = x[16n1+t]; output v[k2] = X[t+16k2]. Unscaled.
// Twiddles: inline serial recurrence (r9 lesson: a twr[16] register array
// blows the 64/128-VGPR budgets and spills; r4 proved the recurrence fits).
template <int S>
__device__ __forceinline__ void fft256_w(float2 v[16], int t, float* lds) {
    fft16<S>(v);
    float2 base = twiddle_base(S, t);
    float2 cur = base;
#pragma unroll
    for (int k = 1; k < 16; ++k) {
        v[k] = cmul(v[k], cur);
        cur = cmul(cur, base);
    }
    asm volatile("" ::: "memory");
#pragma unroll
    for (int k = 0; k < 16; ++k) lds[k * 17 + t] = v[k].x;
    asm volatile("" ::: "memory");
#pragma unroll
    for (int j = 0; j < 16; ++j) v[j].x = lds[t * 17 + j];
    asm volatile("" ::: "memory");
#pragma unroll
    for (int k = 0; k < 16; ++k) lds[k * 17 + t] = v[k].y;
    asm volatile("" ::: "memory");
#pragma unroll
    for (int j = 0; j < 16; ++j) v[j].y = lds[t * 17 + j];
    fft16<S>(v);
}

// Block-synchronous variant for k_col_final (groups span waves there).
template <int S>
__device__ __forceinline__ void fft256_b(float2 v[16], int t, float* ldsRe, float* ldsIm) {
    fft16<S>(v);
    float2 base = twiddle_base(S, t);
    float2 cur = base;
#pragma unroll
    for (int k = 1; k < 16; ++k) {
        v[k] = cmul(v[k], cur);
        cur = cmul(cur, base);
    }
    __syncthreads();
#pragma unroll
    for (int k = 0; k < 16; ++k) {
        ldsRe[k * 17 + t] = v[k].x;
        ldsIm[k * 17 + t] = v[k].y;
    }
    __syncthreads();
#pragma unroll
    for (int j = 0; j < 16; ++j) {
        v[j].x = ldsRe[t * 17 + j];
        v[j].y = ldsIm[t * 17 + j];
    }
    fft16<S>(v);
}

#define ROWSTRIDE 272
#define COLSTRIDE 290
#define TSTRIDE 258  // half2 units; 258%32==2. With the XOR-16-row-parity
                     // swizzle below, transpose writes AND reads are <=2-way.

// =====================================================================
// Mega kernel v2: entire image chain in registers of a 1024-thread block.
// 64 groups x 16 lanes (4 groups per wave -> ALL ffts wave-synchronous).
// Row phases: group g owns rows y = g + 64r (r=0..3), STRAIGHT D[r][n].
// Col phases: group g owns cols x = g + 64a, PERM D[n>>2][4a+(n&3)]
//   (px(col g+64a, row 64q+16j+t) lives at D[q][4a+j]).
// Per-thread data = 64 px = D[4][16] half2 = 64 VGPR; peak live ~115.
// __launch_bounds__(1024): 16-wave block forces the 128-VGPR cap -> fits
// (r5-7 lesson: 512-thread/220-reg demand spilled ~100 regs = 900 MB scratch).
// LDS: union of fft scratch (64 grp x 272 f32 = 69632 B) and transpose tile
// T[64][258] half2 (66048 B).
// =====================================================================

__device__ __forceinline__ void transposeA(__half2 (&D)[4][16], int g, int t,
                                           __half2 (*T)[TSTRIDE]) {
#pragma unroll
    for (int cc = 0; cc < 4; ++cc) {
        __syncthreads();
        int swzw = (g & 1) << 4;  // row=g parity
#pragma unroll
        for (int k = 0; k < 16; ++k) T[g][(16 * k + t) ^ swzw] = D[cc][k];
        __syncthreads();
        int swzr = (t & 1) << 4;  // row=16j+t parity
#pragma unroll
        for (int a = 0; a < 4; ++a)
#pragma unroll
            for (int j = 0; j < 4; ++j)
                D[cc][4 * a + j] = T[16 * j + t][(g + 64 * a) ^ swzr];
    }
    __syncthreads();
}

__device__ __forceinline__ void transposeB(__half2 (&D)[4][16], int g, int t,
                                           __half2 (*T)[TSTRIDE]) {
#pragma unroll
    for (int cc = 0; cc < 4; ++cc) {
        __syncthreads();
        int swzr = (t & 1) << 4;
#pragma unroll
        for (int a = 0; a < 4; ++a)
#pragma unroll
            for (int j = 0; j < 4; ++j)
                T[16 * j + t][(g + 64 * a) ^ swzr] = D[cc][4 * a + j];
        __syncthreads();
        int swzw = (g & 1) << 4;
#pragma unroll
        for (int k = 0; k < 16; ++k) D[cc][k] = T[g][(16 * k + t) ^ swzw];
    }
    __syncthreads();
}

__global__ __launch_bounds__(1024) void k_mega(
        const float* __restrict__ probe, const float* __restrict__ opr_w,
        const float2* __restrict__ sharedK, const float* __restrict__ object,
        const float* __restrict__ positions, const int* __restrict__ indices,
        const float2* __restrict__ tfT, __half2* __restrict__ buf, int b0) {
    __shared__ __align__(16) char UB[69632];
    float* sc = (float*)UB;
    __half2 (*T)[TSTRIDE] = (__half2(*)[TSTRIDE])UB;

    int tt = threadIdx.x;
    int t = tt & 15, g = tt >> 4;  // g in 0..63
    int m = blockIdx.x, bl = blockIdx.y;
    int b = b0 + bl;
    float* scg = sc + g * 272;

    int idx = indices[b];
    float py = positions[idx * 2 + 0], px = positions[idx * 2 + 1];
    float fr0 = py - rintf(py), fr1 = px - rintf(px);
    int r0 = (int)rintf(py), r1 = (int)rintf(px);

    __half2 D[4][16];
    float2 v[16];

    // ---- R1: straight row-FFT'd data ----
    if (m == 0) {
        float w0 = opr_w[idx * 4 + 0], w1 = opr_w[idx * 4 + 1];
        float w2 = opr_w[idx * 4 + 2], w3 = opr_w[idx * 4 + 3];
        const float2* p = (const float2*)probe;
#pragma unroll
        for (int r = 0; r < 4; ++r) {
            int y = g + 64 * r;
            size_t rb = (size_t)y * 256;
#pragma unroll
            for (int n = 0; n < 16; ++n) {
                size_t o = rb + n * 16 + t;
                float2 p0 = p[o];
                float2 p1 = p[(size_t)(1 * NM) * 65536 + o];
                float2 p2 = p[(size_t)(2 * NM) * 65536 + o];
                float2 p3 = p[(size_t)(3 * NM) * 65536 + o];
                v[n] = make_float2(w0 * p0.x + w1 * p1.x + w2 * p2.x + w3 * p3.x,
                                   w0 * p0.y + w1 * p1.y + w2 * p2.y + w3 * p3.y);
            }
            fft256_w<-1>(v, t, scg);
#pragma unroll
            for (int k = 0; k < 16; ++k) D[r][k] = f2h(v[k]);
        }
    } else {
        const float2* sk = sharedK + (size_t)(m - 1) * 65536;
#pragma unroll
        for (int r = 0; r < 4; ++r) {
            int y = g + 64 * r;
#pragma unroll
            for (int k = 0; k < 16; ++k)
                D[r][k] = f2h(sk[(size_t)y * 256 + 16 * k + t]);
        }
    }

    transposeA(D, g, t, T);

    // ---- C1: col FFT * subpixel phase * col IFFT (perm layout) ----
    {
        float fy0 = (float)t * (1.0f / 256.0f);
        float sn, cs;
        __sincosf(-6.2831853071795864769f * fr0 * (1.0f / 16.0f), &sn, &cs);
        float2 step = make_float2(cs, sn);
        __sincosf(6.2831853071795864769f * fr0, &sn, &cs);
        float2 wrap = make_float2(cs, sn);
#pragma unroll
        for (int a = 0; a < 4; ++a) {
            int x = g + 64 * a;
#pragma unroll
            for (int n = 0; n < 16; ++n) v[n] = h2f(D[n >> 2][4 * a + (n & 3)]);
            fft256_w<-1>(v, t, scg);
            float fxv = (float)((x < 128) ? x : x - 256) * (1.0f / 256.0f);
            __sincosf(-6.2831853071795864769f * (fr0 * fy0 + fr1 * fxv), &sn, &cs);
            float2 cur = make_float2(cs, sn);
#pragma unroll
            for (int k2 = 0; k2 < 16; ++k2) {
                if (k2 == 8) cur = cmul(cur, wrap);
                v[k2] = cmul(v[k2], cur);
                cur = cmul(cur, step);
            }
            fft256_w<1>(v, t, scg);
#pragma unroll
            for (int k = 0; k < 16; ++k)
                D[k >> 2][4 * a + (k & 3)] =
                    f2h(make_float2(v[k].x * (1.0f / 256.0f), v[k].y * (1.0f / 256.0f)));
        }
    }

    transposeB(D, g, t, T);

    __half2* ob = buf + (size_t)(bl * NM + m) * 65536;

    // ---- multislice: R (rowIFFT * obj * rowFFT) then C (colFFT * TF * colIFFT) ----
    for (int s = 0; s < NS; ++s) {
        const float2* obase = (const float2*)object + (size_t)s * HOBJ * HOBJ;
#pragma unroll
        for (int r = 0; r < 4; ++r) {
            int y = g + 64 * r;
#pragma unroll
            for (int n = 0; n < 16; ++n) v[n] = h2f(D[r][n]);
            fft256_w<1>(v, t, scg);
            const float2* orow = obase + (size_t)(r0 + y) * HOBJ + r1;
#pragma unroll
            for (int j = 0; j < 16; ++j) {
                float2 pz = orow[t + 16 * j];
                float2 ps = make_float2(v[j].x * (1.0f / 256.0f), v[j].y * (1.0f / 256.0f));
                v[j] = cmul(ps, pz);
            }
            fft256_w<-1>(v, t, scg);
            if (s == NS - 1) {
#pragma unroll
                for (int k = 0; k < 16; ++k)
                    ob[(size_t)y * 256 + 16 * k + t] = f2h(v[k]);
            } else {
#pragma unroll
                for (int k = 0; k < 16; ++k) D[r][k] = f2h(v[k]);
            }
        }
        if (s < NS - 1) {
            transposeA(D, g, t, T);
#pragma unroll
            for (int a = 0; a < 4; ++a) {
                int x = g + 64 * a;
#pragma unroll
                for (int n = 0; n < 16; ++n) v[n] = h2f(D[n >> 2][4 * a + (n & 3)]);
                fft256_w<-1>(v, t, scg);
                const float2* tcol = tfT + (size_t)x * 256;
#pragma unroll
                for (int k2 = 0; k2 < 16; ++k2)
                    v[k2] = cmul(v[k2], tcol[t + 16 * k2]);
                fft256_w<1>(v, t, scg);
#pragma unroll
                for (int k = 0; k < 16; ++k)
                    D[k >> 2][4 * a + (k & 3)] =
                        f2h(make_float2(v[k].x * (1.0f / 256.0f), v[k].y * (1.0f / 256.0f)));
            }
            transposeB(D, g, t, T);
        }
    }
}

// ---------- shared row FFT of probe modes 1..7 (batch-independent, fp32) ----------
__global__ void k_init_shared(const float* __restrict__ probe, float2* __restrict__ sharedK) {
    __shared__ float scm[16 * ROWSTRIDE];
    int tt = threadIdx.x;
    int t = tt & 15, g = tt >> 4;
    int rowg = blockIdx.x, m = blockIdx.y + 1;
    int y = rowg * 16 + g;
    const float2* p = (const float2*)probe + (size_t)m * 65536 + (size_t)y * 256;
    float2 v[16];
#pragma unroll
    for (int n1 = 0; n1 < 16; ++n1) v[n1] = p[n1 * 16 + t];
    fft256_w<-1>(v, t, &scm[g * ROWSTRIDE]);
    float2* ob = sharedK + (size_t)(m - 1) * 65536 + (size_t)y * 256;
#pragma unroll
    for (int k2 = 0; k2 < 16; ++k2) ob[k2 * 16 + t] = v[k2];
}

// ---------- pass E: final col FFT, |.|^2, 4 modes per block, partial sums ----------
__global__ void k_col_final(const __half2* __restrict__ buf, float* __restrict__ out,
                            float* __restrict__ part, int b0) {
    __shared__ float sRe[16 * COLSTRIDE], sIm[16 * COLSTRIDE];
    int tt = threadIdx.x;
    int c = tt & 15, t = tt >> 4;
    int colg = blockIdx.x, mp = blockIdx.y, bl = blockIdx.z;
    int x = colg * 16 + c;
    float acc[16];
#pragma unroll
    for (int j = 0; j < 16; ++j) acc[j] = 0.f;
#pragma unroll
    for (int mi = 0; mi < 4; ++mi) {
        int m = mp * 4 + mi;
        const __half2* img = buf + (size_t)(bl * NM + m) * 65536;
        float2 v[16];
#pragma unroll
        for (int n1 = 0; n1 < 16; ++n1) v[n1] = h2f(img[(size_t)(n1 * 16 + t) * 256 + x]);
        fft256_b<-1>(v, t, &sRe[c * COLSTRIDE], &sIm[c * COLSTRIDE]);
#pragma unroll
        for (int k2 = 0; k2 < 16; ++k2)
            acc[k2] = fmaf(v[k2].x, v[k2].x, fmaf(v[k2].y, v[k2].y, acc[k2]));
    }
    int b = b0 + bl;
    float* ob = (mp ? part : out) + (size_t)b * 65536;
    int xs = (x + 128) & 255;
#pragma unroll
    for (int k2 = 0; k2 < 16; ++k2) {
        int ky = t + 16 * k2;
        int ys = (ky + 128) & 255;
        ob[ys * 256 + xs] = acc[k2] * (1.0f / 65536.0f);
    }
}

__global__ void k_addout(float* __restrict__ out, const float* __restrict__ part) {
    int i = blockIdx.x * 256 + threadIdx.x;
    float4 a = ((const float4*)out)[i];
    float4 p = ((const float4*)part)[i];
    ((float4*)out)[i] = make_float4(a.x + p.x, a.y + p.y, a.z + p.z, a.w + p.w);
}

// ---------- TF precompute, TRANSPOSED layout tfT[x*256 + ky], unscaled ----------
__global__ void k_tf(float2* __restrict__ tfT) {
    int i = blockIdx.x * 256 + threadIdx.x;
    int x = i >> 8, ky = i & 255;
    double fy = (double)((ky < 128) ? ky : ky - 256) / (256.0 * 1.0e-8);
    double fx = (double)((x < 128) ? x : x - 256) / (256.0 * 1.0e-8);
    double ly = 1.24e-10 * fy, lx = 1.24e-10 * fx;
    double arg = 1.0 - lx * lx - ly * ly;
    float2 r = make_float2(0.f, 0.f);
    if (arg > 0.0) {
        double kz = (2.0 * M_PI / 1.24e-10) * sqrt(arg);
        double ph = 2.0e-6 * kz;
        r = make_float2((float)cos(ph), (float)sin(ph));
    }
    tfT[i] = r;
}

extern "C" void kernel_launch(void* const* d_in, const int* in_sizes, int n_in,
                              void* d_out, int out_size, void* d_ws, size_t ws_size,
                              hipStream_t stream) {
    const float* object = (const float*)d_in[0];
    const float* probe = (const float*)d_in[1];
    const float* opr_w = (const float*)d_in[2];
    const float* positions = (const float*)d_in[3];
    const int* indices = (const int*)d_in[4];
    float* out = (float*)d_out;

    float2* tfT = (float2*)d_ws;                                    // 512 KB @ 0
    float2* sharedK = (float2*)((char*)d_ws + ((size_t)1 << 20));   // 3.5 MB @ 1 MB
    float* part = (float*)((char*)d_ws + ((size_t)8 << 20));        // 8 MB @ 8 MB
    __half2* buf = (__half2*)((char*)d_ws + ((size_t)16 << 20));    // fp16 psi @ 16 MB
    size_t head = (size_t)16 << 20;
    size_t avail = (ws_size > head) ? ws_size - head : 0;
    long long perb = (long long)NM * 65536 * sizeof(__half2);       // 2 MB per batch entry
    int Bc = (int)(avail / perb);
    if (Bc > NB) Bc = NB;
    if (Bc < 1) Bc = 1;

    k_tf<<<256, 256, 0, stream>>>(tfT);
    k_init_shared<<<dim3(16, NM - 1, 1), 256, 0, stream>>>(probe, sharedK);

    for (int b0 = 0; b0 < NB; b0 += Bc) {
        int bc = (NB - b0 < Bc) ? (NB - b0) : Bc;
        k_mega<<<dim3(NM, bc), 1024, 0, stream>>>(probe, opr_w, sharedK, object,
                                                  positions, indices, tfT, buf, b0);
        dim3 gridE(16, 2, bc);
        k_col_final<<<gridE, 256, 0, stream>>>(buf, out, part, b0);
    }
    k_addout<<<(NB * 65536) / (256 * 4), 256, 0, stream>>>(out, part);
}

// Round 11
// 467.168 us; speedup vs baseline: 2.1093x; 2.1093x over previous
//
#include <hip/hip_runtime.h>
#include <hip/hip_fp16.h>
#include <math.h>

#define HP 256
#define NB 32
#define NM 8
#define NK 4
#define NS 4
#define HOBJ 1024

// ---------- complex helpers ----------
__device__ __forceinline__ float2 cmul(float2 a, float2 b) {
    return make_float2(fmaf(a.x, b.x, -a.y * b.y), fmaf(a.x, b.y, a.y * b.x));
}
__device__ __forceinline__ float2 h2f(__half2 h) {
    return make_float2(__low2float(h), __high2float(h));
}
__device__ __forceinline__ __half2 f2h(float2 v) {
    return __floats2half2_rn(v.x, v.y);
}

// cos/sin(2*pi*j/16) for j=0..9
__constant__ float COS16[10] = {1.f, 0.9238795325f, 0.7071067812f, 0.3826834324f, 0.f,
                                -0.3826834324f, -0.7071067812f, -0.9238795325f, -1.f, -0.9238795325f};
__constant__ float SIN16[10] = {0.f, 0.3826834324f, 0.7071067812f, 0.9238795325f, 1.f,
                                0.9238795325f, 0.7071067812f, 0.3826834324f, 0.f, -0.3826834324f};

template <int S>
__device__ __forceinline__ void dft4(float2 a, float2 b, float2 c, float2 d,
                                     float2* o0, float2* o1, float2* o2, float2* o3) {
    float2 apc = make_float2(a.x + c.x, a.y + c.y);
    float2 amc = make_float2(a.x - c.x, a.y - c.y);
    float2 bpd = make_float2(b.x + d.x, b.y + d.y);
    float2 bmd = make_float2(b.x - d.x, b.y - d.y);
    float2 ib = (S < 0) ? make_float2(bmd.y, -bmd.x) : make_float2(-bmd.y, bmd.x);
    *o0 = make_float2(apc.x + bpd.x, apc.y + bpd.y);
    *o1 = make_float2(amc.x + ib.x, amc.y + ib.y);
    *o2 = make_float2(apc.x - bpd.x, apc.y - bpd.y);
    *o3 = make_float2(amc.x - ib.x, amc.y - ib.y);
}

template <int S>
__device__ __forceinline__ void fft16(float2 v[16]) {
    float2 t[16];
#pragma unroll
    for (int b = 0; b < 4; ++b)
        dft4<S>(v[b], v[4 + b], v[8 + b], v[12 + b],
                &t[4 * b + 0], &t[4 * b + 1], &t[4 * b + 2], &t[4 * b + 3]);
#pragma unroll
    for (int b = 1; b < 4; ++b)
#pragma unroll
        for (int c = 1; c < 4; ++c) {
            int j = b * c;
            float2 w = make_float2(COS16[j], (S < 0) ? -SIN16[j] : SIN16[j]);
            t[4 * b + c] = cmul(t[4 * b + c], w);
        }
#pragma unroll
    for (int c = 0; c < 4; ++c)
        dft4<S>(t[c], t[4 + c], t[8 + c], t[12 + c],
                &v[c + 0], &v[c + 4], &v[c + 8], &v[c + 12]);
}

__device__ __forceinline__ float2 twiddle_base(int S, int t) {
    float sn, cs;
    __sincosf((float)S * 0.0245436926f /*2pi/256*/ * (float)t, &sn, &cs);
    return make_float2(cs, sn);
}

#define GSTRIDE 273  // float2 units per 16-lane group scratch.
// Bank derivation: byte addr = 8*(273*grp + 17*k + lane) -> bank =
// 2*(grp + k + lane) mod 32 (since 2*273*grp == 2*grp mod 32). For both lane
// geometries here (grp 0..3 x lane 0..15 per wave, and grp 0..15 x lane 0..3)
// every bank-pair is hit EXACTLY 4 times per wave instruction = the 512B/128B
// hardware minimum -> full throughput, write and read phases.

// 256-point FFT, wave-synchronous: 16-lane group inside ONE wave.
// Input v[n1] = x[16n1+t]; output v[k2] = X[t+16k2]. Unscaled.
// Twiddles: inline serial recurrence (r8: LDS table shifts cost to LDS pipe;
// r9: twr[16] register array spills at the 64-VGPR budget).
// Transpose: ONE float2 (b64) round = 32 LDS instr vs r4's 64 b32 (same bytes).
template <int S>
__device__ __forceinline__ void fft256_w(float2 v[16], int t, float2* lds) {
    fft16<S>(v);
    float2 base = twiddle_base(S, t);
    float2 cur = base;
#pragma unroll
    for (int k = 1; k < 16; ++k) {
        v[k] = cmul(v[k], cur);
        cur = cmul(cur, base);
    }
    asm volatile("" ::: "memory");
#pragma unroll
    for (int k = 0; k < 16; ++k) lds[k * 17 + t] = v[k];
    asm volatile("" ::: "memory");
#pragma unroll
    for (int j = 0; j < 16; ++j) v[j] = lds[t * 17 + j];
    fft16<S>(v);
}

// Block-synchronous variant (groups span waves: col kernels). 2 barriers.
template <int S>
__device__ __forceinline__ void fft256_b(float2 v[16], int t, float2* lds) {
    fft16<S>(v);
    float2 base = twiddle_base(S, t);
    float2 cur = base;
#pragma unroll
    for (int k = 1; k < 16; ++k) {
        v[k] = cmul(v[k], cur);
        cur = cmul(cur, base);
    }
    __syncthreads();
#pragma unroll
    for (int k = 0; k < 16; ++k) lds[k * 17 + t] = v[k];
    __syncthreads();
#pragma unroll
    for (int j = 0; j < 16; ++j) v[j] = lds[t * 17 + j];
    fft16<S>(v);
}

// ---------- pass A0: shared row FFT of probe modes 1..7 (fp32 out) ----------
__global__ void k_init_shared(const float* __restrict__ probe, float2* __restrict__ sharedK) {
    __shared__ float2 sc[16 * GSTRIDE];
    int tt = threadIdx.x;
    int t = tt & 15, g = tt >> 4;
    int rowg = blockIdx.x, m = blockIdx.y + 1;
    int y = rowg * 16 + g;
    const float2* p = (const float2*)probe + (size_t)m * 65536 + (size_t)y * 256;
    float2 v[16];
#pragma unroll
    for (int n1 = 0; n1 < 16; ++n1) v[n1] = p[n1 * 16 + t];
    fft256_w<-1>(v, t, &sc[g * GSTRIDE]);
    float2* ob = sharedK + (size_t)(m - 1) * 65536 + (size_t)y * 256;
#pragma unroll
    for (int k2 = 0; k2 < 16; ++k2) ob[k2 * 16 + t] = v[k2];
}

// ---------- pass A1: OPR-weighted mode-0 probe + row FFT -> fp16 buf ----------
__global__ void k_init_m0(const float* __restrict__ probe, const float* __restrict__ opr_w,
                          const int* __restrict__ indices, __half2* __restrict__ buf, int b0) {
    __shared__ float2 sc[16 * GSTRIDE];
    int tt = threadIdx.x;
    int t = tt & 15, g = tt >> 4;
    int rowg = blockIdx.x, bl = blockIdx.z;
    int b = b0 + bl;
    int y = rowg * 16 + g;
    int idx = indices[b];
    float w0 = opr_w[idx * 4 + 0], w1 = opr_w[idx * 4 + 1];
    float w2 = opr_w[idx * 4 + 2], w3 = opr_w[idx * 4 + 3];
    const float2* p = (const float2*)probe;
    size_t rb = (size_t)y * 256;
    float2 v[16];
#pragma unroll
    for (int n1 = 0; n1 < 16; ++n1) {
        size_t o = rb + n1 * 16 + t;
        float2 p0 = p[o];
        float2 p1 = p[(size_t)(1 * NM) * 65536 + o];
        float2 p2 = p[(size_t)(2 * NM) * 65536 + o];
        float2 p3 = p[(size_t)(3 * NM) * 65536 + o];
        v[n1] = make_float2(w0 * p0.x + w1 * p1.x + w2 * p2.x + w3 * p3.x,
                            w0 * p0.y + w1 * p1.y + w2 * p2.y + w3 * p3.y);
    }
    fft256_w<-1>(v, t, &sc[g * GSTRIDE]);
    __half2* ob = buf + (size_t)(bl * NM) * 65536 + (size_t)y * 256;
#pragma unroll
    for (int k2 = 0; k2 < 16; ++k2) ob[k2 * 16 + t] = f2h(v[k2]);
}

// ---------- pass B: col FFT * subpixel phase * col IFFT ----------
// m==0 reads fp16 buf (in-place); m>=1 reads the fp32 shared row-FFT'd probe.
__global__ void k_col_shift(const float* __restrict__ positions, const int* __restrict__ indices,
                            const float2* __restrict__ sharedK, __half2* __restrict__ buf, int b0) {
    __shared__ float2 sc[16 * GSTRIDE];
    int tt = threadIdx.x;
    int c = tt & 15, t = tt >> 4;
    int colg = blockIdx.x, m = blockIdx.y, bl = blockIdx.z;
    int b = b0 + bl;
    int x = colg * 16 + c;
    int idx = indices[b];
    float py = positions[idx * 2 + 0], px = positions[idx * 2 + 1];
    float fr0 = py - rintf(py), fr1 = px - rintf(px);
    float2 v[16];
    if (m) {
        const float2* src = sharedK + (size_t)(m - 1) * 65536;
#pragma unroll
        for (int n1 = 0; n1 < 16; ++n1) v[n1] = src[(size_t)(n1 * 16 + t) * 256 + x];
    } else {
        const __half2* src = buf + (size_t)(bl * NM) * 65536;
#pragma unroll
        for (int n1 = 0; n1 < 16; ++n1) v[n1] = h2f(src[(size_t)(n1 * 16 + t) * 256 + x]);
    }
    __half2* dst = buf + (size_t)(bl * NM + m) * 65536;
    fft256_b<-1>(v, t, &sc[c * GSTRIDE]);
    // separable phase: exp(-2pi*i*(fr0*fy(ky) + fr1*fx(x))), ky = t + 16*k2.
    float fxv = (float)((x < 128) ? x : x - 256) * (1.0f / 256.0f);
    float fy0 = (float)t * (1.0f / 256.0f);
    float sn, cs;
    __sincosf(-6.2831853071795864769f * (fr0 * fy0 + fr1 * fxv), &sn, &cs);
    float2 cur = make_float2(cs, sn);
    __sincosf(-6.2831853071795864769f * fr0 * (1.0f / 16.0f), &sn, &cs);
    float2 step = make_float2(cs, sn);
    __sincosf(6.2831853071795864769f * fr0, &sn, &cs);
    float2 wrap = make_float2(cs, sn);
#pragma unroll
    for (int k2 = 0; k2 < 16; ++k2) {
        if (k2 == 8) cur = cmul(cur, wrap);
        v[k2] = cmul(v[k2], cur);
        cur = cmul(cur, step);
    }
    fft256_b<1>(v, t, &sc[c * GSTRIDE]);
#pragma unroll
    for (int j = 0; j < 16; ++j) {
        float2 r = make_float2(v[j].x * (1.0f / 256.0f), v[j].y * (1.0f / 256.0f));
        dst[(size_t)(j * 16 + t) * 256 + x] = f2h(r);
    }
}

// ---------- pass C: row IFFT * object patch * row FFT (wave-synchronous) ----------
__global__ void k_row_prop(const float* __restrict__ object, const float* __restrict__ positions,
                           const int* __restrict__ indices, __half2* __restrict__ buf, int b0, int s) {
    __shared__ float2 sc[16 * GSTRIDE];
    int tt = threadIdx.x;
    int t = tt & 15, g = tt >> 4;
    int rowg = blockIdx.x, m = blockIdx.y, bl = blockIdx.z;
    int b = b0 + bl;
    int y = rowg * 16 + g;
    int idx = indices[b];
    int r0 = (int)rintf(positions[idx * 2 + 0]);
    int r1 = (int)rintf(positions[idx * 2 + 1]);
    __half2* img = buf + (size_t)(bl * NM + m) * 65536 + (size_t)y * 256;
    float2 v[16];
#pragma unroll
    for (int n1 = 0; n1 < 16; ++n1) v[n1] = h2f(img[n1 * 16 + t]);
    fft256_w<1>(v, t, &sc[g * GSTRIDE]);
    const float2* obj = (const float2*)object + (size_t)s * HOBJ * HOBJ + (size_t)(r0 + y) * HOBJ + r1;
#pragma unroll
    for (int j = 0; j < 16; ++j) {
        int xx = t + 16 * j;
        float2 pz = obj[xx];
        float2 ps = make_float2(v[j].x * (1.0f / 256.0f), v[j].y * (1.0f / 256.0f));
        v[j] = cmul(ps, pz);
    }
    fft256_w<-1>(v, t, &sc[g * GSTRIDE]);
#pragma unroll
    for (int k2 = 0; k2 < 16; ++k2) img[k2 * 16 + t] = f2h(v[k2]);
}

// ---------- pass D: col FFT * TF * col IFFT (TF pre-scaled by 1/256) ----------
__global__ void k_col_tf(const float2* __restrict__ tf, __half2* __restrict__ buf) {
    __shared__ float2 sc[16 * GSTRIDE];
    int tt = threadIdx.x;
    int c = tt & 15, t = tt >> 4;
    int colg = blockIdx.x, m = blockIdx.y, bl = blockIdx.z;
    int x = colg * 16 + c;
    __half2* img = buf + (size_t)(bl * NM + m) * 65536;
    float2 v[16];
#pragma unroll
    for (int n1 = 0; n1 < 16; ++n1) v[n1] = h2f(img[(size_t)(n1 * 16 + t) * 256 + x]);
    fft256_b<-1>(v, t, &sc[c * GSTRIDE]);
#pragma unroll
    for (int k2 = 0; k2 < 16; ++k2) {
        int ky = t + 16 * k2;
        v[k2] = cmul(v[k2], tf[ky * 256 + x]);
    }
    fft256_b<1>(v, t, &sc[c * GSTRIDE]);
#pragma unroll
    for (int j = 0; j < 16; ++j)
        img[(size_t)(j * 16 + t) * 256 + x] = f2h(v[j]);
}

// ---------- pass E: final col FFT, |.|^2, 4 modes per block, partial sums ----------
__global__ void k_col_final(const __half2* __restrict__ buf, float* __restrict__ out,
                            float* __restrict__ part, int b0) {
    __shared__ float2 sc[16 * GSTRIDE];
    int tt = threadIdx.x;
    int c = tt & 15, t = tt >> 4;
    int colg = blockIdx.x, mp = blockIdx.y, bl = blockIdx.z;
    int x = colg * 16 + c;
    float acc[16];
#pragma unroll
    for (int j = 0; j < 16; ++j) acc[j] = 0.f;
#pragma unroll
    for (int mi = 0; mi < 4; ++mi) {
        int m = mp * 4 + mi;
        const __half2* img = buf + (size_t)(bl * NM + m) * 65536;
        float2 v[16];
#pragma unroll
        for (int n1 = 0; n1 < 16; ++n1) v[n1] = h2f(img[(size_t)(n1 * 16 + t) * 256 + x]);
        fft256_b<-1>(v, t, &sc[c * GSTRIDE]);
#pragma unroll
        for (int k2 = 0; k2 < 16; ++k2)
            acc[k2] = fmaf(v[k2].x, v[k2].x, fmaf(v[k2].y, v[k2].y, acc[k2]));
    }
    int b = b0 + bl;
    float* ob = (mp ? part : out) + (size_t)b * 65536;
    int xs = (x + 128) & 255;
#pragma unroll
    for (int k2 = 0; k2 < 16; ++k2) {
        int ky = t + 16 * k2;
        int ys = (ky + 128) & 255;
        ob[ys * 256 + xs] = acc[k2] * (1.0f / 65536.0f);
    }
}

__global__ void k_addout(float* __restrict__ out, const float* __restrict__ part) {
    int i = blockIdx.x * 256 + threadIdx.x;
    float4 a = ((const float4*)out)[i];
    float4 p = ((const float4*)part)[i];
    ((float4*)out)[i] = make_float4(a.x + p.x, a.y + p.y, a.z + p.z, a.w + p.w);
}

// ---------- TF precompute, pre-scaled by 1/256 (IFFT norm folded in) ----------
__global__ void k_tf(float2* __restrict__ tf) {
    int i = blockIdx.x * 256 + threadIdx.x;
    int ky = i >> 8, kx = i & 255;
    double fy = (double)((ky < 128) ? ky : ky - 256) / (256.0 * 1.0e-8);
    double fx = (double)((kx < 128) ? kx : kx - 256) / (256.0 * 1.0e-8);
    double ly = 1.24e-10 * fy, lx = 1.24e-10 * fx;
    double arg = 1.0 - lx * lx - ly * ly;
    float2 r = make_float2(0.f, 0.f);
    if (arg > 0.0) {
        double kz = (2.0 * M_PI / 1.24e-10) * sqrt(arg);
        double ph = 2.0e-6 * kz;
        r = make_float2((float)(cos(ph) / 256.0), (float)(sin(ph) / 256.0));
    }
    tf[i] = r;
}

extern "C" void kernel_launch(void* const* d_in, const int* in_sizes, int n_in,
                              void* d_out, int out_size, void* d_ws, size_t ws_size,
                              hipStream_t stream) {
    const float* object = (const float*)d_in[0];
    const float* probe = (const float*)d_in[1];
    const float* opr_w = (const float*)d_in[2];
    const float* positions = (const float*)d_in[3];
    const int* indices = (const int*)d_in[4];
    float* out = (float*)d_out;

    float2* tf = (float2*)d_ws;                                     // 512 KB @ 0
    float2* sharedK = (float2*)((char*)d_ws + ((size_t)1 << 20));   // 3.5 MB @ 1 MB
    float* part = (float*)((char*)d_ws + ((size_t)8 << 20));        // 8 MB @ 8 MB
    __half2* buf = (__half2*)((char*)d_ws + ((size_t)16 << 20));    // fp16 psi @ 16 MB
    size_t head = (size_t)16 << 20;
    size_t avail = (ws_size > head) ? ws_size - head : 0;
    long long perb = (long long)NM * 65536 * sizeof(__half2);       // 2 MB per batch entry
    int Bc = (int)(avail / perb);
    if (Bc > NB) Bc = NB;
    if (Bc < 1) Bc = 1;

    k_tf<<<256, 256, 0, stream>>>(tf);
    k_init_shared<<<dim3(16, NM - 1, 1), 256, 0, stream>>>(probe, sharedK);

    for (int b0 = 0; b0 < NB; b0 += Bc) {
        int bc = (NB - b0 < Bc) ? (NB - b0) : Bc;
        dim3 grid(16, NM, bc);
        k_init_m0<<<dim3(16, 1, bc), 256, 0, stream>>>(probe, opr_w, indices, buf, b0);
        k_col_shift<<<grid, 256, 0, stream>>>(positions, indices, sharedK, buf, b0);
        for (int s = 0; s < NS; ++s) {
            k_row_prop<<<grid, 256, 0, stream>>>(object, positions, indices, buf, b0, s);
            if (s < NS - 1) k_col_tf<<<grid, 256, 0, stream>>>(tf, buf);
        }
        dim3 gridE(16, 2, bc);
        k_col_final<<<gridE, 256, 0, stream>>>(buf, out, part, b0);
    }
    k_addout<<<(NB * 65536) / (256 * 4), 256, 0, stream>>>(out, part);
}

// Round 12
// 396.480 us; speedup vs baseline: 2.4853x; 1.1783x over previous
//
#include <hip/hip_runtime.h>
#include <hip/hip_fp16.h>
#include <math.h>

#define HP 256
#define NB 32
#define NM 8
#define NK 4
#define NS 4
#define HOBJ 1024

// ---------- complex helpers ----------
__device__ __forceinline__ float2 cmul(float2 a, float2 b) {
    return make_float2(fmaf(a.x, b.x, -a.y * b.y), fmaf(a.x, b.y, a.y * b.x));
}

// fp16 psi storage: half2 per complex (4 B). Compute stays fp32.
__device__ __forceinline__ float2 h2f(__half2 h) {
    return make_float2(__low2float(h), __high2float(h));
}
__device__ __forceinline__ __half2 f2h(float2 v) {
    return __floats2half2_rn(v.x, v.y);
}

// cos/sin(2*pi*j/16) for j=0..9
__constant__ float COS16[10] = {1.f, 0.9238795325f, 0.7071067812f, 0.3826834324f, 0.f,
                                -0.3826834324f, -0.7071067812f, -0.9238795325f, -1.f, -0.9238795325f};
__constant__ float SIN16[10] = {0.f, 0.3826834324f, 0.7071067812f, 0.9238795325f, 1.f,
                                0.9238795325f, 0.7071067812f, 0.3826834324f, 0.f, -0.3826834324f};

// 4-point DFT, S=-1 forward, S=+1 inverse (unscaled)
template <int S>
__device__ __forceinline__ void dft4(float2 a, float2 b, float2 c, float2 d,
                                     float2* o0, float2* o1, float2* o2, float2* o3) {
    float2 apc = make_float2(a.x + c.x, a.y + c.y);
    float2 amc = make_float2(a.x - c.x, a.y - c.y);
    float2 bpd = make_float2(b.x + d.x, b.y + d.y);
    float2 bmd = make_float2(b.x - d.x, b.y - d.y);
    float2 ib = (S < 0) ? make_float2(bmd.y, -bmd.x) : make_float2(-bmd.y, bmd.x);
    *o0 = make_float2(apc.x + bpd.x, apc.y + bpd.y);
    *o1 = make_float2(amc.x + ib.x, amc.y + ib.y);
    *o2 = make_float2(apc.x - bpd.x, apc.y - bpd.y);
    *o3 = make_float2(amc.x - ib.x, amc.y - ib.y);
}

// in-register 16-point FFT (unscaled), natural order in/out
template <int S>
__device__ __forceinline__ void fft16(float2 v[16]) {
    float2 t[16];
#pragma unroll
    for (int b = 0; b < 4; ++b)
        dft4<S>(v[b], v[4 + b], v[8 + b], v[12 + b],
                &t[4 * b + 0], &t[4 * b + 1], &t[4 * b + 2], &t[4 * b + 3]);
#pragma unroll
    for (int b = 1; b < 4; ++b)
#pragma unroll
        for (int c = 1; c < 4; ++c) {
            int j = b * c;
            float2 w = make_float2(COS16[j], (S < 0) ? -SIN16[j] : SIN16[j]);
            t[4 * b + c] = cmul(t[4 * b + c], w);
        }
#pragma unroll
    for (int c = 0; c < 4; ++c)
        dft4<S>(t[c], t[4 + c], t[8 + c], t[12 + c],
                &v[c + 0], &v[c + 4], &v[c + 8], &v[c + 12]);
}

__device__ __forceinline__ float2 twiddle_base(int S, int t) {
    float sn, cs;
    __sincosf((float)S * 0.0245436926f /*2pi/256*/ * (float)t, &sn, &cs);
    return make_float2(cs, sn);
}

// 256-point FFT, wave-synchronous variant: 16-lane group inside ONE wave.
// Single LDS array, Re and Im sequentially; compile-time fences only, no s_barrier.
template <int S>
__device__ __forceinline__ void fft256_w(float2 v[16], int t, float* lds) {
    fft16<S>(v);
    float2 base = twiddle_base(S, t);
    float2 cur = base;
#pragma unroll
    for (int k = 1; k < 16; ++k) {
        v[k] = cmul(v[k], cur);
        cur = cmul(cur, base);
    }
    asm volatile("" ::: "memory");
#pragma unroll
    for (int k = 0; k < 16; ++k) lds[k * 17 + t] = v[k].x;
    asm volatile("" ::: "memory");
#pragma unroll
    for (int j = 0; j < 16; ++j) v[j].x = lds[t * 17 + j];
    asm volatile("" ::: "memory");
#pragma unroll
    for (int k = 0; k < 16; ++k) lds[k * 17 + t] = v[k].y;
    asm volatile("" ::: "memory");
#pragma unroll
    for (int j = 0; j < 16; ++j) v[j].y = lds[t * 17 + j];
    fft16<S>(v);
}

// 256-point FFT, block-synchronous variant: group spans waves (col kernels).
// Two LDS arrays, only 2 __syncthreads per call.
template <int S>
__device__ __forceinline__ void fft256_b(float2 v[16], int t, float* ldsRe, float* ldsIm) {
    fft16<S>(v);
    float2 base = twiddle_base(S, t);
    float2 cur = base;
#pragma unroll
    for (int k = 1; k < 16; ++k) {
        v[k] = cmul(v[k], cur);
        cur = cmul(cur, base);
    }
    __syncthreads();
#pragma unroll
    for (int k = 0; k < 16; ++k) {
        ldsRe[k * 17 + t] = v[k].x;
        ldsIm[k * 17 + t] = v[k].y;
    }
    __syncthreads();
#pragma unroll
    for (int j = 0; j < 16; ++j) {
        v[j].x = ldsRe[t * 17 + j];
        v[j].y = ldsIm[t * 17 + j];
    }
    fft16<S>(v);
}

#define ROWSTRIDE 272
#define COLSTRIDE 290

// ---------- pass A0: shared row FFT of probe modes 1..7 (batch-independent, fp32 out) ----------
__global__ void k_init_shared(const float* __restrict__ probe, float2* __restrict__ sharedK) {
    __shared__ float sc[16 * ROWSTRIDE];
    int tt = threadIdx.x;
    int t = tt & 15, g = tt >> 4;
    int rowg = blockIdx.x, m = blockIdx.y + 1;  // m = 1..7
    int y = rowg * 16 + g;
    const float2* p = (const float2*)probe + (size_t)m * 65536 + (size_t)y * 256;
    float2 v[16];
#pragma unroll
    for (int n1 = 0; n1 < 16; ++n1) v[n1] = p[n1 * 16 + t];
    fft256_w<-1>(v, t, &sc[g * ROWSTRIDE]);
    float2* ob = sharedK + (size_t)(m - 1) * 65536 + (size_t)y * 256;
#pragma unroll
    for (int k2 = 0; k2 < 16; ++k2) ob[k2 * 16 + t] = v[k2];
}

// ---------- pass A1: OPR-weighted mode-0 probe + row FFT -> fp16 buf ----------
__global__ void k_init_m0(const float* __restrict__ probe, const float* __restrict__ opr_w,
                          const int* __restrict__ indices, __half2* __restrict__ buf, int b0) {
    __shared__ float sc[16 * ROWSTRIDE];
    int tt = threadIdx.x;
    int t = tt & 15, g = tt >> 4;
    int rowg = blockIdx.x, bl = blockIdx.z;
    int b = b0 + bl;
    int y = rowg * 16 + g;
    int idx = indices[b];
    float w0 = opr_w[idx * 4 + 0], w1 = opr_w[idx * 4 + 1];
    float w2 = opr_w[idx * 4 + 2], w3 = opr_w[idx * 4 + 3];
    const float2* p = (const float2*)probe;
    size_t rb = (size_t)y * 256;
    float2 v[16];
#pragma unroll
    for (int n1 = 0; n1 < 16; ++n1) {
        size_t o = rb + n1 * 16 + t;
        float2 p0 = p[o];
        float2 p1 = p[(size_t)(1 * NM) * 65536 + o];
        float2 p2 = p[(size_t)(2 * NM) * 65536 + o];
        float2 p3 = p[(size_t)(3 * NM) * 65536 + o];
        v[n1] = make_float2(w0 * p0.x + w1 * p1.x + w2 * p2.x + w3 * p3.x,
                            w0 * p0.y + w1 * p1.y + w2 * p2.y + w3 * p3.y);
    }
    fft256_w<-1>(v, t, &sc[g * ROWSTRIDE]);
    __half2* ob = buf + (size_t)(bl * NM) * 65536 + (size_t)y * 256;
#pragma unroll
    for (int k2 = 0; k2 < 16; ++k2) ob[k2 * 16 + t] = f2h(v[k2]);
}

// ---------- pass B: col FFT * subpixel phase * col IFFT ----------
// m==0 reads fp16 buf (in-place); m>=1 reads the fp32 shared row-FFT'd probe (LLC-hot).
__global__ void k_col_shift(const float* __restrict__ positions, const int* __restrict__ indices,
                            const float2* __restrict__ sharedK, __half2* __restrict__ buf, int b0) {
    __shared__ float sRe[16 * COLSTRIDE], sIm[16 * COLSTRIDE];
    int tt = threadIdx.x;
    int c = tt & 15, t = tt >> 4;
    int colg = blockIdx.x, m = blockIdx.y, bl = blockIdx.z;
    int b = b0 + bl;
    int x = colg * 16 + c;
    int idx = indices[b];
    float py = positions[idx * 2 + 0], px = positions[idx * 2 + 1];
    float fr0 = py - rintf(py), fr1 = px - rintf(px);
    float2 v[16];
    if (m) {
        const float2* src = sharedK + (size_t)(m - 1) * 65536;
#pragma unroll
        for (int n1 = 0; n1 < 16; ++n1) v[n1] = src[(size_t)(n1 * 16 + t) * 256 + x];
    } else {
        const __half2* src = buf + (size_t)(bl * NM) * 65536;
#pragma unroll
        for (int n1 = 0; n1 < 16; ++n1) v[n1] = h2f(src[(size_t)(n1 * 16 + t) * 256 + x]);
    }
    __half2* dst = buf + (size_t)(bl * NM + m) * 65536;
    fft256_b<-1>(v, t, &sRe[c * COLSTRIDE], &sIm[c * COLSTRIDE]);
    // separable phase: exp(-2pi*i*(fr0*fy(ky) + fr1*fx(x))), ky = t + 16*k2.
    float fxv = (float)((x < 128) ? x : x - 256) * (1.0f / 256.0f);
    float fy0 = (float)t * (1.0f / 256.0f);
    float sn, cs;
    __sincosf(-6.2831853071795864769f * (fr0 * fy0 + fr1 * fxv), &sn, &cs);
    float2 cur = make_float2(cs, sn);
    __sincosf(-6.2831853071795864769f * fr0 * (1.0f / 16.0f), &sn, &cs);
    float2 step = make_float2(cs, sn);
    __sincosf(6.2831853071795864769f * fr0, &sn, &cs);
    float2 wrap = make_float2(cs, sn);
#pragma unroll
    for (int k2 = 0; k2 < 16; ++k2) {
        if (k2 == 8) cur = cmul(cur, wrap);
        v[k2] = cmul(v[k2], cur);
        cur = cmul(cur, step);
    }
    fft256_b<1>(v, t, &sRe[c * COLSTRIDE], &sIm[c * COLSTRIDE]);
#pragma unroll
    for (int j = 0; j < 16; ++j) {
        float2 r = make_float2(v[j].x * (1.0f / 256.0f), v[j].y * (1.0f / 256.0f));
        dst[(size_t)(j * 16 + t) * 256 + x] = f2h(r);
    }
}

// ---------- pass C: row IFFT * object patch * row FFT (wave-synchronous, no barriers) ----------
__global__ void k_row_prop(const float* __restrict__ object, const float* __restrict__ positions,
                           const int* __restrict__ indices, __half2* __restrict__ buf, int b0, int s) {
    __shared__ float sc[16 * ROWSTRIDE];
    int tt = threadIdx.x;
    int t = tt & 15, g = tt >> 4;
    int rowg = blockIdx.x, m = blockIdx.y, bl = blockIdx.z;
    int b = b0 + bl;
    int y = rowg * 16 + g;
    int idx = indices[b];
    int r0 = (int)rintf(positions[idx * 2 + 0]);
    int r1 = (int)rintf(positions[idx * 2 + 1]);
    __half2* img = buf + (size_t)(bl * NM + m) * 65536 + (size_t)y * 256;
    float2 v[16];
#pragma unroll
    for (int n1 = 0; n1 < 16; ++n1) v[n1] = h2f(img[n1 * 16 + t]);
    fft256_w<1>(v, t, &sc[g * ROWSTRIDE]);
    const float2* obj = (const float2*)object + (size_t)s * HOBJ * HOBJ + (size_t)(r0 + y) * HOBJ + r1;
#pragma unroll
    for (int j = 0; j < 16; ++j) {
        int xx = t + 16 * j;
        float2 pz = obj[xx];
        float2 ps = make_float2(v[j].x * (1.0f / 256.0f), v[j].y * (1.0f / 256.0f));
        v[j] = cmul(ps, pz);
    }
    fft256_w<-1>(v, t, &sc[g * ROWSTRIDE]);
#pragma unroll
    for (int k2 = 0; k2 < 16; ++k2) img[k2 * 16 + t] = f2h(v[k2]);
}

// ---------- pass D: col FFT * TF * col IFFT ----------
__global__ void k_col_tf(const float2* __restrict__ tf, __half2* __restrict__ buf) {
    __shared__ float sRe[16 * COLSTRIDE], sIm[16 * COLSTRIDE];
    int tt = threadIdx.x;
    int c = tt & 15, t = tt >> 4;
    int colg = blockIdx.x, m = blockIdx.y, bl = blockIdx.z;
    int x = colg * 16 + c;
    __half2* img = buf + (size_t)(bl * NM + m) * 65536;
    float2 v[16];
#pragma unroll
    for (int n1 = 0; n1 < 16; ++n1) v[n1] = h2f(img[(size_t)(n1 * 16 + t) * 256 + x]);
    fft256_b<-1>(v, t, &sRe[c * COLSTRIDE], &sIm[c * COLSTRIDE]);
#pragma unroll
    for (int k2 = 0; k2 < 16; ++k2) {
        int ky = t + 16 * k2;
        v[k2] = cmul(v[k2], tf[ky * 256 + x]);
    }
    fft256_b<1>(v, t, &sRe[c * COLSTRIDE], &sIm[c * COLSTRIDE]);
#pragma unroll
    for (int j = 0; j < 16; ++j) {
        float2 r = make_float2(v[j].x * (1.0f / 256.0f), v[j].y * (1.0f / 256.0f));
        img[(size_t)(j * 16 + t) * 256 + x] = f2h(r);
    }
}

// ---------- pass E: final col FFT, |.|^2, 4 modes per block, partial sums, shifted store ----------
__global__ void k_col_final(const __half2* __restrict__ buf, float* __restrict__ out,
                            float* __restrict__ part, int b0) {
    __shared__ float sRe[16 * COLSTRIDE], sIm[16 * COLSTRIDE];
    int tt = threadIdx.x;
    int c = tt & 15, t = tt >> 4;
    int colg = blockIdx.x, mp = blockIdx.y, bl = blockIdx.z;
    int x = colg * 16 + c;
    float acc[16];
#pragma unroll
    for (int j = 0; j < 16; ++j) acc[j] = 0.f;
#pragma unroll
    for (int mi = 0; mi < 4; ++mi) {
        int m = mp * 4 + mi;
        const __half2* img = buf + (size_t)(bl * NM + m) * 65536;
        float2 v[16];
#pragma unroll
        for (int n1 = 0; n1 < 16; ++n1) v[n1] = h2f(img[(size_t)(n1 * 16 + t) * 256 + x]);
        fft256_b<-1>(v, t, &sRe[c * COLSTRIDE], &sIm[c * COLSTRIDE]);
#pragma unroll
        for (int k2 = 0; k2 < 16; ++k2)
            acc[k2] = fmaf(v[k2].x, v[k2].x, fmaf(v[k2].y, v[k2].y, acc[k2]));
    }
    int b = b0 + bl;
    float* ob = (mp ? part : out) + (size_t)b * 65536;
    int xs = (x + 128) & 255;
#pragma unroll
    for (int k2 = 0; k2 < 16; ++k2) {
        int ky = t + 16 * k2;
        int ys = (ky + 128) & 255;
        ob[ys * 256 + xs] = acc[k2] * (1.0f / 65536.0f);
    }
}

// ---------- out += part ----------
__global__ void k_addout(float* __restrict__ out, const float* __restrict__ part) {
    int i = blockIdx.x * 256 + threadIdx.x;
    float4 a = ((const float4*)out)[i];
    float4 p = ((const float4*)part)[i];
    ((float4*)out)[i] = make_float4(a.x + p.x, a.y + p.y, a.z + p.z, a.w + p.w);
}

// ---------- TF precompute (double precision: phase ~1e5 rad) ----------
__global__ void k_tf(float2* __restrict__ tf) {
    int i = blockIdx.x * 256 + threadIdx.x;
    int ky = i >> 8, kx = i & 255;
    double fy = (double)((ky < 128) ? ky : ky - 256) / (256.0 * 1.0e-8);
    double fx = (double)((kx < 128) ? kx : kx - 256) / (256.0 * 1.0e-8);
    double ly = 1.24e-10 * fy, lx = 1.24e-10 * fx;
    double arg = 1.0 - lx * lx - ly * ly;
    float2 r = make_float2(0.f, 0.f);
    if (arg > 0.0) {
        double kz = (2.0 * M_PI / 1.24e-10) * sqrt(arg);
        double ph = 2.0e-6 * kz;
        r = make_float2((float)cos(ph), (float)sin(ph));
    }
    tf[i] = r;
}

extern "C" void kernel_launch(void* const* d_in, const int* in_sizes, int n_in,
                              void* d_out, int out_size, void* d_ws, size_t ws_size,
                              hipStream_t stream) {
    const float* object = (const float*)d_in[0];
    const float* probe = (const float*)d_in[1];
    const float* opr_w = (const float*)d_in[2];
    const float* positions = (const float*)d_in[3];
    const int* indices = (const int*)d_in[4];
    float* out = (float*)d_out;

    float2* tf = (float2*)d_ws;                                     // 512 KB @ 0
    float2* sharedK = (float2*)((char*)d_ws + ((size_t)1 << 20));   // 3.5 MB @ 1 MB
    float* part = (float*)((char*)d_ws + ((size_t)8 << 20));        // 8 MB @ 8 MB
    __half2* buf = (__half2*)((char*)d_ws + ((size_t)16 << 20));    // fp16 psi @ 16 MB
    size_t head = (size_t)16 << 20;
    size_t avail = (ws_size > head) ? ws_size - head : 0;
    long long perb = (long long)NM * 65536 * sizeof(__half2);       // 2 MB per batch entry
    int Bc = (int)(avail / perb);
    if (Bc > NB) Bc = NB;
    if (Bc < 1) Bc = 1;

    k_tf<<<256, 256, 0, stream>>>(tf);
    k_init_shared<<<dim3(16, NM - 1, 1), 256, 0, stream>>>(probe, sharedK);

    for (int b0 = 0; b0 < NB; b0 += Bc) {
        int bc = (NB - b0 < Bc) ? (NB - b0) : Bc;
        dim3 grid(16, NM, bc);
        k_init_m0<<<dim3(16, 1, bc), 256, 0, stream>>>(probe, opr_w, indices, buf, b0);
        k_col_shift<<<grid, 256, 0, stream>>>(positions, indices, sharedK, buf, b0);
        for (int s = 0; s < NS; ++s) {
            k_row_prop<<<grid, 256, 0, stream>>>(object, positions, indices, buf, b0, s);
            if (s < NS - 1) k_col_tf<<<grid, 256, 0, stream>>>(tf, buf);
        }
        dim3 gridE(16, 2, bc);
        k_col_final<<<gridE, 256, 0, stream>>>(buf, out, part, b0);
    }
    k_addout<<<(NB * 65536) / (256 * 4), 256, 0, stream>>>(out, part);
}